// Round 12
// baseline (189.892 us; speedup 1.0000x reference)
//
#include <hip/hip_runtime.h>
#include <hip/hip_bf16.h>
#include <float.h>

#define BB 2
#define NN 256
#define DD 64
#define KK 16
#define NH 4
#define HID 128
#define KVD 256
#define RH 64
#define NNODES (BB*NN)      // 512
#define NEDGES (NNODES*KK)  // 8192

typedef unsigned int uint32;
typedef unsigned short ushort_t;
typedef float f32x4_t __attribute__((ext_vector_type(4)));
typedef short bf16x8_t __attribute__((ext_vector_type(8)));
typedef __attribute__((address_space(3))) ushort_t lds_us;
typedef __attribute__((address_space(1))) const ushort_t glb_us;

__device__ __forceinline__ uint32 cvtpk_bf16(float lo, float hi) {
  uint32 r;
  asm("v_cvt_pk_bf16_f32 %0, %1, %2" : "=v"(r) : "v"(lo), "v"(hi));
  return r;
}

__device__ __forceinline__ float wave_sum64(float v) {
  #pragma unroll
  for (int m = 32; m; m >>= 1) v += __shfl_xor(v, m, 64);
  return v;
}

__device__ __forceinline__ ushort_t rne_bf16(float f) {
  uint32 u = __float_as_uint(f);
  return (ushort_t)((u + 0x7FFFu + ((u >> 16) & 1u)) >> 16);
}

// ---------------- Kernel 1: [0..127] prenorm+q/xi/xj | [128..647] W3->bf16 swizzled
//                  [648..711] Wkv -> bf16 TRANSPOSED [n][k]  (verified round 11) ---
__global__ __launch_bounds__(256) void node_w3_kernel(
    const float* __restrict__ feat, const float* __restrict__ gscale,
    const float* __restrict__ Wq, const float* __restrict__ Wxi,
    const float* __restrict__ Wxj,
    const float* __restrict__ W3, const float* __restrict__ b3,
    const float* __restrict__ Wkv,
    float* __restrict__ q_ws, float* __restrict__ xi_ws, float* __restrict__ xj_ws,
    ushort_t* __restrict__ W3bf, ushort_t* __restrict__ Wkvt) {
  int bx = blockIdx.x;
  if (bx >= 648) {
    int i = ((bx - 648) * 256 + threadIdx.x) * 4;
    int n = i >> 8, k0 = i & 255;
    union { uint2 q; ushort_t s[4]; } o;
    #pragma unroll
    for (int j = 0; j < 4; ++j) o.s[j] = rne_bf16(Wkv[(k0 + j) * KVD + n]);
    *(uint2*)(Wkvt + n * KVD + k0) = o.q;
    return;
  }
  if (bx >= 128) {
    const int W3N = 64 * KVD * DD;               // 1,048,576
    int i = ((bx - 128) * 256 + threadIdx.x) * 8;
    const float* src = (i < W3N) ? (W3 + i) : (b3 + (i - W3N));
    float4 a = ((const float4*)src)[0];
    float4 b = ((const float4*)src)[1];
    float v[8] = {a.x, a.y, a.z, a.w, b.x, b.y, b.z, b.w};
    union { uint4 q; ushort_t s[8]; } o;
    #pragma unroll
    for (int jj = 0; jj < 8; ++jj) o.s[jj] = rne_bf16(v[jj]);
    int rr = i >> 14, j0 = i & 16383;
    int oc = j0 >> 6, gr = (j0 >> 3) & 7;
    int byte_sw = oc * 128 + ((gr * 16) ^ ((oc & 7) << 4));
    *(uint4*)(W3bf + (rr << 14) + (byte_sw >> 1)) = o.q;
    return;
  }
  int sub = threadIdx.x >> 6;
  int t = threadIdx.x & 63;
  int node = bx * 4 + sub;
  __shared__ float xs[4][DD];
  float f = feat[node * DD + t];
  float ss = wave_sum64(f * f);
  float rms = sqrtf(ss) * 0.125f;
  float den = fmaxf(rms, 1e-12f);
  float x = f / den * gscale[t];
  xs[sub][t] = x;
  __syncthreads();
  float q0 = 0.f, q1 = 0.f, xiv = 0.f, xjv = 0.f;
  #pragma unroll 4
  for (int d = 0; d < DD; ++d) {
    float xv = xs[sub][d];
    q0  += xv * Wq[d * HID + t];
    q1  += xv * Wq[d * HID + 64 + t];
    xiv += xv * Wxi[d * DD + t];
    xjv += xv * Wxj[d * DD + t];
  }
  q_ws[node * HID + t] = q0;
  q_ws[node * HID + 64 + t] = q1;
  xi_ws[node * DD + t] = xiv;
  xj_ws[node * DD + t] = xjv;
}

// ---------------- Kernel 2: FUSED edge-MLP + kv-MFMA + attention ------------------
// Block b (256 thr = 4 waves): edges [b*32,+32) = nodes {2b, 2b+1}.
//  Phase E: radial MLP (W2 in regs, readlane broadcast) + xe gather -> LDS
//  Phase KV: 65 W3bf rows staged via global_load_lds (2-phase dbuf, 32KB/row);
//            wave wv computes o-cols [wv*64,+64) for all 32 edges (16 MFMA/row)
//  Phase A: kv -> LDS (16B-unit XOR swizzle), per-node MFMA kv@Wkvt + softmax + Wout
#define AFRAG(dst, arr, base, h) {                                \
  union { bf16x8_t v; uint32 u[4]; } t_;                          \
  t_.u[0] = cvtpk_bf16(arr[(base)+0]*(h), arr[(base)+1]*(h));     \
  t_.u[1] = cvtpk_bf16(arr[(base)+2]*(h), arr[(base)+3]*(h));     \
  t_.u[2] = cvtpk_bf16(arr[(base)+4]*(h), arr[(base)+5]*(h));     \
  t_.u[3] = cvtpk_bf16(arr[(base)+6]*(h), arr[(base)+7]*(h));     \
  dst = t_.v; }

#define STAGE2(buf, rr) {                                                      \
  const ushort_t* s_ = W3bf + ((size_t)(rr) << 14);                            \
  ushort_t* d_ = &bstage[buf][0];                                              \
  __builtin_amdgcn_global_load_lds((glb_us*)(s_ + tid * 8),         (lds_us*)(d_ + tid * 8),         16, 0, 0); \
  __builtin_amdgcn_global_load_lds((glb_us*)(s_ + 2048  + tid * 8), (lds_us*)(d_ + 2048  + tid * 8), 16, 0, 0); \
  __builtin_amdgcn_global_load_lds((glb_us*)(s_ + 4096  + tid * 8), (lds_us*)(d_ + 4096  + tid * 8), 16, 0, 0); \
  __builtin_amdgcn_global_load_lds((glb_us*)(s_ + 6144  + tid * 8), (lds_us*)(d_ + 6144  + tid * 8), 16, 0, 0); \
  __builtin_amdgcn_global_load_lds((glb_us*)(s_ + 8192  + tid * 8), (lds_us*)(d_ + 8192  + tid * 8), 16, 0, 0); \
  __builtin_amdgcn_global_load_lds((glb_us*)(s_ + 10240 + tid * 8), (lds_us*)(d_ + 10240 + tid * 8), 16, 0, 0); \
  __builtin_amdgcn_global_load_lds((glb_us*)(s_ + 12288 + tid * 8), (lds_us*)(d_ + 12288 + tid * 8), 16, 0, 0); \
  __builtin_amdgcn_global_load_lds((glb_us*)(s_ + 14336 + tid * 8), (lds_us*)(d_ + 14336 + tid * 8), 16, 0, 0); }

__global__ __launch_bounds__(256, 1) void fused_kernel(
    const int* __restrict__ nbi, const float* __restrict__ rel,
    const float* __restrict__ W1, const float* __restrict__ b1,
    const float* __restrict__ g1, const float* __restrict__ W2,
    const float* __restrict__ b2, const float* __restrict__ g2,
    const float* __restrict__ xi_ws, const float* __restrict__ xj_ws,
    const ushort_t* __restrict__ W3bf, const ushort_t* __restrict__ Wkvt,
    const float* __restrict__ q_ws, const int* __restrict__ maskp,
    const float* __restrict__ Wout, float* __restrict__ out) {
  int b = blockIdx.x;
  int tid = threadIdx.x;
  int wv = tid >> 6, l = tid & 63;
  int l15 = l & 15, g = l >> 4;

  __shared__ ushort_t bstage[2][16384];   // 2 x 32KB; bstage[0] reused as kvs f32
  __shared__ float h2_s[32 * 68];
  __shared__ float xe_s[32 * 68];
  __shared__ float attn_s[2][NH * KK];
  __shared__ float o_s[2][HID];

  STAGE2(0, 0);   // prefetch W3 row 0 under the edge phase

  // ---------------- Phase E: radial MLP + gather (wave wv: edges wv*8..+8)
  {
    float w1r = W1[l], b1r = b1[l], g1r = g1[l];
    float b2r = b2[l], g2r = g2[l];
    float w2r[64];
    #pragma unroll
    for (int r = 0; r < 64; ++r) w2r[r] = W2[r * RH + l];
    int node_w = b * 2 + (wv >> 1);
    int bbn = node_w >> 8;
    float xir = xi_ws[node_w * DD + l];
    for (int i = 0; i < 8; ++i) {
      int e_loc = wv * 8 + i;
      float rd = rel[b * 32 + e_loc];
      float h = rd * w1r + b1r;
      h = h / (1.f + expf(-h));                       // silu
      float mu = wave_sum64(h) * (1.f / RH);
      float c = h - mu;
      float var = wave_sum64(c * c) * (1.f / RH);
      float xn = c * rsqrtf(var + 1e-5f) * g1r;
      float p = b2r;
      #pragma unroll
      for (int r = 0; r < 64; ++r) {
        float s = __uint_as_float(__builtin_amdgcn_readlane(__float_as_uint(xn), r));
        p += s * w2r[r];
      }
      p = p / (1.f + expf(-p));
      mu = wave_sum64(p) * (1.f / RH);
      c = p - mu;
      var = wave_sum64(c * c) * (1.f / RH);
      float h2v = c * rsqrtf(var + 1e-5f) * g2r;
      h2_s[e_loc * 68 + l] = h2v;
      int nb = nbi[node_w * KK + (e_loc & 15)];
      xe_s[e_loc * 68 + l] = xj_ws[(bbn * NN + nb) * DD + l] + xir;
    }
  }
  asm volatile("s_waitcnt vmcnt(0)" ::: "memory");
  __syncthreads();

  // ---------------- Phase KV
  float xfA[16], xfB[16];
  #pragma unroll
  for (int j = 0; j < 8; ++j) {
    xfA[j]     = xe_s[l15 * 68 + g * 8 + j];
    xfA[8 + j] = xe_s[l15 * 68 + 32 + g * 8 + j];
    xfB[j]     = xe_s[(16 + l15) * 68 + g * 8 + j];
    xfB[8 + j] = xe_s[(16 + l15) * 68 + 32 + g * 8 + j];
  }
  int swz = (l15 & 7) << 4;
  f32x4_t accA[4], accB[4];
  #pragma unroll
  for (int oi = 0; oi < 4; ++oi) {
    accA[oi] = (f32x4_t){0.f, 0.f, 0.f, 0.f};
    accB[oi] = (f32x4_t){0.f, 0.f, 0.f, 0.f};
  }
  int cur = 0;
  for (int p = 0; p <= 64; ++p) {
    if (p < 64) STAGE2(cur ^ 1, p + 1);
    float hA = (p < 64) ? h2_s[l15 * 68 + p] : 1.0f;
    float hB = (p < 64) ? h2_s[(16 + l15) * 68 + p] : 1.0f;
    bf16x8_t a0A, a1A, a0B, a1B;
    AFRAG(a0A, xfA, 0, hA); AFRAG(a1A, xfA, 8, hA);
    AFRAG(a0B, xfB, 0, hB); AFRAG(a1B, xfB, 8, hB);
    const char* bp = (const char*)&bstage[cur][0] + wv * 8192 + l15 * 128;
    #pragma unroll
    for (int oi = 0; oi < 4; ++oi) {
      bf16x8_t bv0 = *(const bf16x8_t*)(bp + oi * 2048 + ((g * 16) ^ swz));
      bf16x8_t bv1 = *(const bf16x8_t*)(bp + oi * 2048 + (((4 + g) * 16) ^ swz));
      accA[oi] = __builtin_amdgcn_mfma_f32_16x16x32_bf16(a0A, bv0, accA[oi], 0, 0, 0);
      accA[oi] = __builtin_amdgcn_mfma_f32_16x16x32_bf16(a1A, bv1, accA[oi], 0, 0, 0);
      accB[oi] = __builtin_amdgcn_mfma_f32_16x16x32_bf16(a0B, bv0, accB[oi], 0, 0, 0);
      accB[oi] = __builtin_amdgcn_mfma_f32_16x16x32_bf16(a1B, bv1, accB[oi], 0, 0, 0);
    }
    asm volatile("s_waitcnt vmcnt(0)" ::: "memory");
    __syncthreads();
    cur ^= 1;
  }

  // ---------------- kv -> LDS (fp32, 16B-unit XOR swizzle: unit ^= e&7)
  float* kvf = (float*)&bstage[0][0];      // 32 x 256 floats = 32 KB
  {
    #pragma unroll
    for (int m = 0; m < 2; ++m) {
      #pragma unroll
      for (int oi = 0; oi < 4; ++oi) {
        f32x4_t av = m ? accB[oi] : accA[oi];
        int f = wv * 64 + oi * 16 + l15;
        int fu = f >> 2, fl = f & 3;
        #pragma unroll
        for (int q = 0; q < 4; ++q) {
          int e = m * 16 + g * 4 + q;
          kvf[e * 256 + ((fu ^ (e & 7)) << 2) + fl] = av[q];
        }
      }
    }
  }
  __syncthreads();

  // ---------------- Phase A: per-node MFMA kv@Wkvt + L2-dist softmax + output
  int role = wv & 1, nl = wv >> 1;         // role 0 = K cols, 1 = V cols
  int node = b * 2 + nl;
  bf16x8_t a[8];
  {
    int e = nl * 16 + l15;
    const float* kr = kvf + e * 256;
    int sw = l15 & 7;
    #pragma unroll
    for (int c = 0; c < 8; ++c) {
      int u0 = (c * 8 + g * 2) ^ sw;
      int u1 = (c * 8 + g * 2 + 1) ^ sw;
      f32x4_t v0 = *(const f32x4_t*)(kr + u0 * 4);
      f32x4_t v1 = *(const f32x4_t*)(kr + u1 * 4);
      union { bf16x8_t v; uint32 u[4]; } t_;
      t_.u[0] = cvtpk_bf16(v0.x, v0.y);
      t_.u[1] = cvtpk_bf16(v0.z, v0.w);
      t_.u[2] = cvtpk_bf16(v1.x, v1.y);
      t_.u[3] = cvtpk_bf16(v1.z, v1.w);
      a[c] = t_.v;
    }
  }
  f32x4_t acc[8];
  #pragma unroll
  for (int nt = 0; nt < 8; ++nt) {
    acc[nt] = (f32x4_t){0.f, 0.f, 0.f, 0.f};
    const ushort_t* bbase = Wkvt + (size_t)(role * 128 + nt * 16 + l15) * KVD + g * 8;
    #pragma unroll
    for (int c = 0; c < 8; ++c) {
      bf16x8_t bv = *(const bf16x8_t*)(bbase + c * 32);
      acc[nt] = __builtin_amdgcn_mfma_f32_16x16x32_bf16(a[c], bv, acc[nt], 0, 0, 0);
    }
  }
  const float scale = 0.17677669529663689f;   // 32^-0.5
  if (role == 0) {
    float sim[4][4];   // [q][h]
    #pragma unroll
    for (int h = 0; h < 4; ++h) {
      #pragma unroll
      for (int q = 0; q < 4; ++q) {
        float s = 0.f;
        #pragma unroll
        for (int pq = 0; pq < 2; ++pq) {
          int nt = h * 2 + pq;
          float qv = q_ws[node * HID + nt * 16 + l15];
          float diff = qv - acc[nt][q] + 1e-6f;
          s += diff * diff;
        }
        #pragma unroll
        for (int m = 8; m; m >>= 1) s += __shfl_xor(s, m, 64);
        sim[q][h] = -sqrtf(s) * scale;
      }
    }
    int mv[4];
    #pragma unroll
    for (int q = 0; q < 4; ++q) mv[q] = maskp[node * KK + g * 4 + q];
    #pragma unroll
    for (int h = 0; h < 4; ++h) {
      float sv[4];
      float mx = -FLT_MAX;
      #pragma unroll
      for (int q = 0; q < 4; ++q) {
        sv[q] = mv[q] ? sim[q][h] : -FLT_MAX;
        mx = fmaxf(mx, sv[q]);
      }
      mx = fmaxf(mx, __shfl_xor(mx, 16, 64));
      mx = fmaxf(mx, __shfl_xor(mx, 32, 64));
      float se = 0.f, ev[4];
      #pragma unroll
      for (int q = 0; q < 4; ++q) { ev[q] = expf(sv[q] - mx); se += ev[q]; }
      se += __shfl_xor(se, 16, 64);
      se += __shfl_xor(se, 32, 64);
      float inv = 1.f / se;
      if (l15 == 0) {
        #pragma unroll
        for (int q = 0; q < 4; ++q) attn_s[nl][h * KK + g * 4 + q] = ev[q] * inv;
      }
    }
  }
  __syncthreads();
  if (role == 1) {
    #pragma unroll
    for (int nt = 0; nt < 8; ++nt) {
      int h = nt >> 1;
      float o = 0.f;
      #pragma unroll
      for (int q = 0; q < 4; ++q) o += attn_s[nl][h * KK + g * 4 + q] * acc[nt][q];
      o += __shfl_xor(o, 16, 64);
      o += __shfl_xor(o, 32, 64);
      if (g == 0) o_s[nl][nt * 16 + l15] = o;
    }
  }
  __syncthreads();
  if (tid < 128) {
    int n2 = tid >> 6, t = tid & 63;
    float r = 0.f;
    #pragma unroll 4
    for (int cI = 0; cI < HID; ++cI) r += o_s[n2][cI] * Wout[cI * DD + t];
    out[(b * 2 + n2) * DD + t] = r;
  }
}

extern "C" void kernel_launch(void* const* d_in, const int* in_sizes, int n_in,
                              void* d_out, int out_size, void* d_ws, size_t ws_size,
                              hipStream_t stream) {
  const float* feat = (const float*)d_in[0];
  const int*   nbi  = (const int*)d_in[1];
  const int*   msk  = (const int*)d_in[2];
  const float* rel  = (const float*)d_in[3];
  const float* gsc  = (const float*)d_in[4];
  const float* Wq   = (const float*)d_in[5];
  const float* Wxi  = (const float*)d_in[6];
  const float* Wxj  = (const float*)d_in[7];
  const float* W1   = (const float*)d_in[8];
  const float* b1   = (const float*)d_in[9];
  const float* g1   = (const float*)d_in[10];
  const float* W2   = (const float*)d_in[11];
  const float* b2   = (const float*)d_in[12];
  const float* g2   = (const float*)d_in[13];
  const float* W3   = (const float*)d_in[14];
  const float* b3   = (const float*)d_in[15];
  const float* Wkv  = (const float*)d_in[16];
  const float* Wout = (const float*)d_in[17];

  float* ws      = (float*)d_ws;
  float* q_ws    = ws;                          // 512*128
  float* xi_ws   = q_ws  + NNODES * HID;        // 512*64
  float* xj_ws   = xi_ws + NNODES * DD;         // 512*64
  ushort_t* W3bf = (ushort_t*)(xj_ws + NNODES * DD);   // 65*16384 bf16 (~2.1 MB)
  ushort_t* Wkvt = W3bf + 65 * 16384;                  // 256*256 bf16 (128 KB)

  node_w3_kernel<<<712, 256, 0, stream>>>(feat, gsc, Wq, Wxi, Wxj, W3, b3, Wkv,
                                          q_ws, xi_ws, xj_ws, W3bf, Wkvt);
  fused_kernel<<<256, 256, 0, stream>>>(nbi, rel, W1, b1, g1, W2, b2, g2,
                                        xi_ws, xj_ws, W3bf, Wkvt,
                                        q_ws, msk, Wout, (float*)d_out);
}

// Round 13
// 166.545 us; speedup vs baseline: 1.1402x; 1.1402x over previous
//
#include <hip/hip_runtime.h>
#include <hip/hip_bf16.h>
#include <float.h>

#define BB 2
#define NN 256
#define DD 64
#define KK 16
#define NH 4
#define HID 128
#define KVD 256
#define RH 64
#define NNODES (BB*NN)      // 512
#define NEDGES (NNODES*KK)  // 8192

typedef unsigned int uint32;
typedef unsigned short ushort_t;
typedef float f32x4_t __attribute__((ext_vector_type(4)));
typedef short bf16x8_t __attribute__((ext_vector_type(8)));
typedef __attribute__((address_space(3))) ushort_t lds_us;
typedef __attribute__((address_space(1))) const ushort_t glb_us;

__device__ __forceinline__ uint32 cvtpk_bf16(float lo, float hi) {
  uint32 r;
  asm("v_cvt_pk_bf16_f32 %0, %1, %2" : "=v"(r) : "v"(lo), "v"(hi));
  return r;
}

__device__ __forceinline__ float wave_sum64(float v) {
  #pragma unroll
  for (int m = 32; m; m >>= 1) v += __shfl_xor(v, m, 64);
  return v;
}

__device__ __forceinline__ ushort_t rne_bf16(float f) {
  uint32 u = __float_as_uint(f);
  return (ushort_t)((u + 0x7FFFu + ((u >> 16) & 1u)) >> 16);
}

// ---------------- Kernel 1: [0..127] prenorm+q/xi/xj | [128..647] W3->bf16 swizzled
//                  [648..711] Wkv -> bf16 TRANSPOSED [n][k]  (verified round 11) ---
__global__ __launch_bounds__(256) void node_w3_kernel(
    const float* __restrict__ feat, const float* __restrict__ gscale,
    const float* __restrict__ Wq, const float* __restrict__ Wxi,
    const float* __restrict__ Wxj,
    const float* __restrict__ W3, const float* __restrict__ b3,
    const float* __restrict__ Wkv,
    float* __restrict__ q_ws, float* __restrict__ xi_ws, float* __restrict__ xj_ws,
    ushort_t* __restrict__ W3bf, ushort_t* __restrict__ Wkvt) {
  int bx = blockIdx.x;
  if (bx >= 648) {
    int i = ((bx - 648) * 256 + threadIdx.x) * 4;
    int n = i >> 8, k0 = i & 255;
    union { uint2 q; ushort_t s[4]; } o;
    #pragma unroll
    for (int j = 0; j < 4; ++j) o.s[j] = rne_bf16(Wkv[(k0 + j) * KVD + n]);
    *(uint2*)(Wkvt + n * KVD + k0) = o.q;
    return;
  }
  if (bx >= 128) {
    const int W3N = 64 * KVD * DD;               // 1,048,576
    int i = ((bx - 128) * 256 + threadIdx.x) * 8;
    const float* src = (i < W3N) ? (W3 + i) : (b3 + (i - W3N));
    float4 a = ((const float4*)src)[0];
    float4 b = ((const float4*)src)[1];
    float v[8] = {a.x, a.y, a.z, a.w, b.x, b.y, b.z, b.w};
    union { uint4 q; ushort_t s[8]; } o;
    #pragma unroll
    for (int jj = 0; jj < 8; ++jj) o.s[jj] = rne_bf16(v[jj]);
    int rr = i >> 14, j0 = i & 16383;
    int oc = j0 >> 6, gr = (j0 >> 3) & 7;
    int byte_sw = oc * 128 + ((gr * 16) ^ ((oc & 7) << 4));
    *(uint4*)(W3bf + (rr << 14) + (byte_sw >> 1)) = o.q;
    return;
  }
  int sub = threadIdx.x >> 6;
  int t = threadIdx.x & 63;
  int node = bx * 4 + sub;
  __shared__ float xs[4][DD];
  float f = feat[node * DD + t];
  float ss = wave_sum64(f * f);
  float rms = sqrtf(ss) * 0.125f;
  float den = fmaxf(rms, 1e-12f);
  float x = f / den * gscale[t];
  xs[sub][t] = x;
  __syncthreads();
  float q0 = 0.f, q1 = 0.f, xiv = 0.f, xjv = 0.f;
  #pragma unroll 4
  for (int d = 0; d < DD; ++d) {
    float xv = xs[sub][d];
    q0  += xv * Wq[d * HID + t];
    q1  += xv * Wq[d * HID + 64 + t];
    xiv += xv * Wxi[d * DD + t];
    xjv += xv * Wxj[d * DD + t];
  }
  q_ws[node * HID + t] = q0;
  q_ws[node * HID + 64 + t] = q1;
  xi_ws[node * DD + t] = xiv;
  xj_ws[node * DD + t] = xjv;
}

// ---------------- Kernel 2: FUSED edge-MLP + kv-MFMA + attention ------------------
// Block b (256 thr = 4 waves): edges [b*32,+32) = nodes {2b, 2b+1}.
//  Phase KV is BARRIER-FREE: wave wv stages & reads only its own 8KB quarter of
//  each W3bf row; depth-3 LDS ring, counted s_waitcnt vmcnt(16) (T4).
#define AFRAG(dst, arr, base, h) {                                \
  union { bf16x8_t v; uint32 u[4]; } t_;                          \
  t_.u[0] = cvtpk_bf16(arr[(base)+0]*(h), arr[(base)+1]*(h));     \
  t_.u[1] = cvtpk_bf16(arr[(base)+2]*(h), arr[(base)+3]*(h));     \
  t_.u[2] = cvtpk_bf16(arr[(base)+4]*(h), arr[(base)+5]*(h));     \
  t_.u[3] = cvtpk_bf16(arr[(base)+6]*(h), arr[(base)+7]*(h));     \
  dst = t_.v; }

// wave wv stages its own quarter (8KB) of W3bf row rr into ring slot `slot`
#define STAGEW(slot, rr) {                                                     \
  const ushort_t* s_ = W3bf + ((size_t)(rr) << 14) + wv * 4096;                \
  ushort_t* d_ = &bstage[slot][wv * 4096];                                     \
  __builtin_amdgcn_global_load_lds((glb_us*)(s_ + l * 8),          (lds_us*)(d_ + l * 8),          16, 0, 0); \
  __builtin_amdgcn_global_load_lds((glb_us*)(s_ + 512  + l * 8),   (lds_us*)(d_ + 512  + l * 8),   16, 0, 0); \
  __builtin_amdgcn_global_load_lds((glb_us*)(s_ + 1024 + l * 8),   (lds_us*)(d_ + 1024 + l * 8),   16, 0, 0); \
  __builtin_amdgcn_global_load_lds((glb_us*)(s_ + 1536 + l * 8),   (lds_us*)(d_ + 1536 + l * 8),   16, 0, 0); \
  __builtin_amdgcn_global_load_lds((glb_us*)(s_ + 2048 + l * 8),   (lds_us*)(d_ + 2048 + l * 8),   16, 0, 0); \
  __builtin_amdgcn_global_load_lds((glb_us*)(s_ + 2560 + l * 8),   (lds_us*)(d_ + 2560 + l * 8),   16, 0, 0); \
  __builtin_amdgcn_global_load_lds((glb_us*)(s_ + 3072 + l * 8),   (lds_us*)(d_ + 3072 + l * 8),   16, 0, 0); \
  __builtin_amdgcn_global_load_lds((glb_us*)(s_ + 3584 + l * 8),   (lds_us*)(d_ + 3584 + l * 8),   16, 0, 0); }

__global__ __launch_bounds__(256, 1) void fused_kernel(
    const int* __restrict__ nbi, const float* __restrict__ rel,
    const float* __restrict__ W1, const float* __restrict__ b1,
    const float* __restrict__ g1, const float* __restrict__ W2,
    const float* __restrict__ b2, const float* __restrict__ g2,
    const float* __restrict__ xi_ws, const float* __restrict__ xj_ws,
    const ushort_t* __restrict__ W3bf, const ushort_t* __restrict__ Wkvt,
    const float* __restrict__ q_ws, const int* __restrict__ maskp,
    const float* __restrict__ Wout, float* __restrict__ out) {
  int b = blockIdx.x;
  int tid = threadIdx.x;
  int wv = tid >> 6, l = tid & 63;
  int l15 = l & 15, g = l >> 4;

  __shared__ ushort_t bstage[3][16384];   // 3 x 32KB ring; [0] reused as kvs f32
  __shared__ float h2_s[32 * 68];
  __shared__ float xe_s[32 * 68];
  __shared__ float attn_s[2][NH * KK];
  __shared__ float o_s[2][HID];

  STAGEW(0, 0);   // prefetch rows 0..2 under the edge phase
  STAGEW(1, 1);
  STAGEW(2, 2);

  // ---------------- Phase E: radial MLP + gather (wave wv: edges wv*8..+8)
  {
    float w1r = W1[l], b1r = b1[l], g1r = g1[l];
    float b2r = b2[l], g2r = g2[l];
    float w2r[64];
    #pragma unroll
    for (int r = 0; r < 64; ++r) w2r[r] = W2[r * RH + l];
    int node_w = b * 2 + (wv >> 1);
    int bbn = node_w >> 8;
    float xir = xi_ws[node_w * DD + l];
    for (int i = 0; i < 8; ++i) {
      int e_loc = wv * 8 + i;
      float rd = rel[b * 32 + e_loc];
      float h = rd * w1r + b1r;
      h = h / (1.f + expf(-h));                       // silu
      float mu = wave_sum64(h) * (1.f / RH);
      float c = h - mu;
      float var = wave_sum64(c * c) * (1.f / RH);
      float xn = c * rsqrtf(var + 1e-5f) * g1r;
      float p = b2r;
      #pragma unroll
      for (int r = 0; r < 64; ++r) {
        float s = __uint_as_float(__builtin_amdgcn_readlane(__float_as_uint(xn), r));
        p += s * w2r[r];
      }
      p = p / (1.f + expf(-p));
      mu = wave_sum64(p) * (1.f / RH);
      c = p - mu;
      var = wave_sum64(c * c) * (1.f / RH);
      float h2v = c * rsqrtf(var + 1e-5f) * g2r;
      h2_s[e_loc * 68 + l] = h2v;
      int nb = nbi[node_w * KK + (e_loc & 15)];
      xe_s[e_loc * 68 + l] = xj_ws[(bbn * NN + nb) * DD + l] + xir;
    }
  }
  __syncthreads();   // h2/xe visible to all waves (this also drains vmcnt: rows 0-2 done)

  // ---------------- Phase KV: barrier-free per-wave stream, depth-3 counted vmcnt
  float xfA[16], xfB[16];
  #pragma unroll
  for (int j = 0; j < 8; ++j) {
    xfA[j]     = xe_s[l15 * 68 + g * 8 + j];
    xfA[8 + j] = xe_s[l15 * 68 + 32 + g * 8 + j];
    xfB[j]     = xe_s[(16 + l15) * 68 + g * 8 + j];
    xfB[8 + j] = xe_s[(16 + l15) * 68 + 32 + g * 8 + j];
  }
  int swz = (l15 & 7) << 4;
  f32x4_t accA[4], accB[4];
  #pragma unroll
  for (int oi = 0; oi < 4; ++oi) {
    accA[oi] = (f32x4_t){0.f, 0.f, 0.f, 0.f};
    accB[oi] = (f32x4_t){0.f, 0.f, 0.f, 0.f};
  }
  #pragma unroll 1
  for (int p = 0; p <= 64; ++p) {
    if (p < 63)       asm volatile("s_waitcnt vmcnt(16)" ::: "memory");
    else if (p == 63) asm volatile("s_waitcnt vmcnt(8)"  ::: "memory");
    else              asm volatile("s_waitcnt vmcnt(0)"  ::: "memory");
    int slot = p - (p / 3) * 3;                        // p % 3
    const char* bp = (const char*)&bstage[slot][0] + wv * 8192 + l15 * 128;
    float hA = (p < 64) ? h2_s[l15 * 68 + p] : 1.0f;
    float hB = (p < 64) ? h2_s[(16 + l15) * 68 + p] : 1.0f;
    bf16x8_t a0A, a1A, a0B, a1B;
    AFRAG(a0A, xfA, 0, hA); AFRAG(a1A, xfA, 8, hA);
    AFRAG(a0B, xfB, 0, hB); AFRAG(a1B, xfB, 8, hB);
    #pragma unroll
    for (int oi = 0; oi < 4; ++oi) {
      bf16x8_t bv0 = *(const bf16x8_t*)(bp + oi * 2048 + ((g * 16) ^ swz));
      bf16x8_t bv1 = *(const bf16x8_t*)(bp + oi * 2048 + (((4 + g) * 16) ^ swz));
      accA[oi] = __builtin_amdgcn_mfma_f32_16x16x32_bf16(a0A, bv0, accA[oi], 0, 0, 0);
      accA[oi] = __builtin_amdgcn_mfma_f32_16x16x32_bf16(a1A, bv1, accA[oi], 0, 0, 0);
      accB[oi] = __builtin_amdgcn_mfma_f32_16x16x32_bf16(a0B, bv0, accB[oi], 0, 0, 0);
      accB[oi] = __builtin_amdgcn_mfma_f32_16x16x32_bf16(a1B, bv1, accB[oi], 0, 0, 0);
    }
    if (p <= 61) STAGEW(slot, p + 3);   // refill just-consumed slot (issue after reads)
  }
  __syncthreads();   // all waves' kv done; drains remaining vmcnt

  // ---------------- kv -> LDS (fp32, 16B-unit XOR swizzle: unit ^= e&7)
  float* kvf = (float*)&bstage[0][0];      // 32 x 256 floats = 32 KB
  {
    #pragma unroll
    for (int m = 0; m < 2; ++m) {
      #pragma unroll
      for (int oi = 0; oi < 4; ++oi) {
        f32x4_t av = m ? accB[oi] : accA[oi];
        int f = wv * 64 + oi * 16 + l15;
        int fu = f >> 2, fl = f & 3;
        #pragma unroll
        for (int q = 0; q < 4; ++q) {
          int e = m * 16 + g * 4 + q;
          kvf[e * 256 + ((fu ^ (e & 7)) << 2) + fl] = av[q];
        }
      }
    }
  }
  __syncthreads();

  // ---------------- Phase A: per-node MFMA kv@Wkvt + L2-dist softmax + output
  int role = wv & 1, nl = wv >> 1;         // role 0 = K cols, 1 = V cols
  int node = b * 2 + nl;
  bf16x8_t a[8];
  {
    int e = nl * 16 + l15;
    const float* kr = kvf + e * 256;
    int sw = l15 & 7;
    #pragma unroll
    for (int c = 0; c < 8; ++c) {
      int u0 = (c * 8 + g * 2) ^ sw;
      int u1 = (c * 8 + g * 2 + 1) ^ sw;
      f32x4_t v0 = *(const f32x4_t*)(kr + u0 * 4);
      f32x4_t v1 = *(const f32x4_t*)(kr + u1 * 4);
      union { bf16x8_t v; uint32 u[4]; } t_;
      t_.u[0] = cvtpk_bf16(v0.x, v0.y);
      t_.u[1] = cvtpk_bf16(v0.z, v0.w);
      t_.u[2] = cvtpk_bf16(v1.x, v1.y);
      t_.u[3] = cvtpk_bf16(v1.z, v1.w);
      a[c] = t_.v;
    }
  }
  f32x4_t acc[8];
  #pragma unroll
  for (int nt = 0; nt < 8; ++nt) {
    acc[nt] = (f32x4_t){0.f, 0.f, 0.f, 0.f};
    const ushort_t* bbase = Wkvt + (size_t)(role * 128 + nt * 16 + l15) * KVD + g * 8;
    #pragma unroll
    for (int c = 0; c < 8; ++c) {
      bf16x8_t bv = *(const bf16x8_t*)(bbase + c * 32);
      acc[nt] = __builtin_amdgcn_mfma_f32_16x16x32_bf16(a[c], bv, acc[nt], 0, 0, 0);
    }
  }
  const float scale = 0.17677669529663689f;   // 32^-0.5
  if (role == 0) {
    float sim[4][4];   // [q][h]
    #pragma unroll
    for (int h = 0; h < 4; ++h) {
      #pragma unroll
      for (int q = 0; q < 4; ++q) {
        float s = 0.f;
        #pragma unroll
        for (int pq = 0; pq < 2; ++pq) {
          int nt = h * 2 + pq;
          float qv = q_ws[node * HID + nt * 16 + l15];
          float diff = qv - acc[nt][q] + 1e-6f;
          s += diff * diff;
        }
        #pragma unroll
        for (int m = 8; m; m >>= 1) s += __shfl_xor(s, m, 64);
        sim[q][h] = -sqrtf(s) * scale;
      }
    }
    int mv[4];
    #pragma unroll
    for (int q = 0; q < 4; ++q) mv[q] = maskp[node * KK + g * 4 + q];
    #pragma unroll
    for (int h = 0; h < 4; ++h) {
      float sv[4];
      float mx = -FLT_MAX;
      #pragma unroll
      for (int q = 0; q < 4; ++q) {
        sv[q] = mv[q] ? sim[q][h] : -FLT_MAX;
        mx = fmaxf(mx, sv[q]);
      }
      mx = fmaxf(mx, __shfl_xor(mx, 16, 64));
      mx = fmaxf(mx, __shfl_xor(mx, 32, 64));
      float se = 0.f, ev[4];
      #pragma unroll
      for (int q = 0; q < 4; ++q) { ev[q] = expf(sv[q] - mx); se += ev[q]; }
      se += __shfl_xor(se, 16, 64);
      se += __shfl_xor(se, 32, 64);
      float inv = 1.f / se;
      if (l15 == 0) {
        #pragma unroll
        for (int q = 0; q < 4; ++q) attn_s[nl][h * KK + g * 4 + q] = ev[q] * inv;
      }
    }
  }
  __syncthreads();
  if (role == 1) {
    #pragma unroll
    for (int nt = 0; nt < 8; ++nt) {
      int h = nt >> 1;
      float o = 0.f;
      #pragma unroll
      for (int q = 0; q < 4; ++q) o += attn_s[nl][h * KK + g * 4 + q] * acc[nt][q];
      o += __shfl_xor(o, 16, 64);
      o += __shfl_xor(o, 32, 64);
      if (g == 0) o_s[nl][nt * 16 + l15] = o;
    }
  }
  __syncthreads();
  if (tid < 128) {
    int n2 = tid >> 6, t = tid & 63;
    float r = 0.f;
    #pragma unroll 4
    for (int cI = 0; cI < HID; ++cI) r += o_s[n2][cI] * Wout[cI * DD + t];
    out[(b * 2 + n2) * DD + t] = r;
  }
}

extern "C" void kernel_launch(void* const* d_in, const int* in_sizes, int n_in,
                              void* d_out, int out_size, void* d_ws, size_t ws_size,
                              hipStream_t stream) {
  const float* feat = (const float*)d_in[0];
  const int*   nbi  = (const int*)d_in[1];
  const int*   msk  = (const int*)d_in[2];
  const float* rel  = (const float*)d_in[3];
  const float* gsc  = (const float*)d_in[4];
  const float* Wq   = (const float*)d_in[5];
  const float* Wxi  = (const float*)d_in[6];
  const float* Wxj  = (const float*)d_in[7];
  const float* W1   = (const float*)d_in[8];
  const float* b1   = (const float*)d_in[9];
  const float* g1   = (const float*)d_in[10];
  const float* W2   = (const float*)d_in[11];
  const float* b2   = (const float*)d_in[12];
  const float* g2   = (const float*)d_in[13];
  const float* W3   = (const float*)d_in[14];
  const float* b3   = (const float*)d_in[15];
  const float* Wkv  = (const float*)d_in[16];
  const float* Wout = (const float*)d_in[17];

  float* ws      = (float*)d_ws;
  float* q_ws    = ws;                          // 512*128
  float* xi_ws   = q_ws  + NNODES * HID;        // 512*64
  float* xj_ws   = xi_ws + NNODES * DD;         // 512*64
  ushort_t* W3bf = (ushort_t*)(xj_ws + NNODES * DD);   // 65*16384 bf16 (~2.1 MB)
  ushort_t* Wkvt = W3bf + 65 * 16384;                  // 256*256 bf16 (128 KB)

  node_w3_kernel<<<712, 256, 0, stream>>>(feat, gsc, Wq, Wxi, Wxj, W3, b3, Wkv,
                                          q_ws, xi_ws, xj_ws, W3bf, Wkvt);
  fused_kernel<<<256, 256, 0, stream>>>(nbi, rel, W1, b1, g1, W2, b2, g2,
                                        xi_ws, xj_ws, W3bf, Wkvt,
                                        q_ws, msk, Wout, (float*)d_out);
}